// Round 4
// baseline (574.498 us; speedup 1.0000x reference)
//
#include <hip/hip_runtime.h>
#include <math.h>

// CRF mean-field, fully factorized (rank-28 Taylor of exp(g.g') x separable
// 3-D Gaussian convs), executed as ONE persistent kernel with hand-rolled
// grid barriers: 116 co-resident blocks (<=256 CUs), 11 grid syncs replace
// 12 inter-launch gaps. Barrier counter is monotonic (epoch-based): a stale
// high value cannot hang, and a memset node zeroes it before each replay.

constexpr int   NT    = 8192;
constexpr int   NB    = 116;                 // 112 bilateral + 4 spatial volumes
constexpr float SQL2E = 1.2011224087864498f; // sqrt(log2 e)
constexpr float LOG2E = 1.4426950408889634f;
constexpr float INVA  = 0.2f * SQL2E;        // spatial prescale

// W rows (NT floats): 0..27 M[ab] | 28 s1 | 29 s2 | 30..33 u1 | 34..37 u2
//                     38..153 cv  | 154 barrier counter
constexpr int R_M = 0, R_S1 = 28, R_S2 = 29, R_U1 = 30, R_U2 = 34, R_CV = 38;
constexpr int R_CNT = 154;

__constant__ float INVSQF[7] = {1.f, 1.f, 0.70710678f, 0.40824829f,
                                0.20412415f, 0.09128709f, 0.03726780f};

static __device__ __forceinline__ float ex2(float x) {
    return __builtin_amdgcn_exp2f(x);
}

static __device__ __forceinline__ void gridbar(unsigned* cnt, unsigned target) {
    __syncthreads();
    if (threadIdx.x == 0) {
        __threadfence();                       // publish block's writes (agent scope)
        atomicAdd(cnt, 1u);
        while (__hip_atomic_load(cnt, __ATOMIC_ACQUIRE, __HIP_MEMORY_SCOPE_AGENT) < target)
            __builtin_amdgcn_s_sleep(1);
        __threadfence();                       // acquire: invalidate stale caches
    }
    __syncthreads();
}

// Separable 3-D Gaussian conv of the volume in SP (512x17-padded), in place,
// result written to global row outp. Layout n = x*256 + y*16 + z.
static __device__ __forceinline__ void conv3d(float* SP, const float* g32,
                                              float* __restrict__ outp, int tid) {
    // z-pass: rows (x,y) at stride 17
#pragma unroll
    for (int rr = 0; rr < 2; rr++) {
        int r = tid + rr * 256;
        float v[16], acc[16];
#pragma unroll
        for (int z = 0; z < 16; z++) { v[z] = SP[r*17 + z]; acc[z] = 0.f; }
#pragma unroll
        for (int zp = 0; zp < 16; zp++)
#pragma unroll
            for (int z = 0; z < 16; z++) {
                int d = (z > zp) ? (z - zp) : (zp - z);
                acc[z] = fmaf(g32[d], v[zp], acc[z]);
            }
#pragma unroll
        for (int z = 0; z < 16; z++) SP[r*17 + z] = acc[z];
    }
    __syncthreads();
    // y-pass: rows (x,z), stride 17 between y's
#pragma unroll
    for (int rr = 0; rr < 2; rr++) {
        int r = tid + rr * 256;
        int base = (r >> 4) * 272 + (r & 15);
        float v[16], acc[16];
#pragma unroll
        for (int y = 0; y < 16; y++) { v[y] = SP[base + y*17]; acc[y] = 0.f; }
#pragma unroll
        for (int yp = 0; yp < 16; yp++)
#pragma unroll
            for (int y = 0; y < 16; y++) {
                int d = (y > yp) ? (y - yp) : (yp - y);
                acc[y] = fmaf(g32[d], v[yp], acc[y]);
            }
#pragma unroll
        for (int y = 0; y < 16; y++) SP[base + y*17] = acc[y];
    }
    __syncthreads();
    // x-pass: rows (y,z), stride 272; write to global
    {
        int base = (tid >> 4) * 17 + (tid & 15);
        float v[32], acc[32];
#pragma unroll
        for (int xp = 0; xp < 32; xp++) { v[xp] = SP[base + xp*272]; acc[xp] = 0.f; }
#pragma unroll
        for (int xp = 0; xp < 32; xp++)
#pragma unroll
            for (int x = 0; x < 32; x++) {
                int d = (x > xp) ? (x - xp) : (xp - x);
                acc[x] = fmaf(g32[d], v[xp], acc[x]);
            }
#pragma unroll
        for (int x = 0; x < 32; x++) outp[x*256 + tid] = acc[x];
    }
}

__global__ __launch_bounds__(256) void k_mega(const float* __restrict__ lu,
        const float* __restrict__ feat, const float* __restrict__ compat,
        float* __restrict__ out, float* __restrict__ W) {
    __shared__ float SP[512 * 17];
    const int bid = blockIdx.x, tid = threadIdx.x;
    unsigned* cnt = (unsigned*)(W + (size_t)R_CNT * NT);
    unsigned bar = 0;
    float g32[32];
#pragma unroll
    for (int d = 0; d < 32; d++) { float t = d * INVA; g32[d] = ex2(-0.5f*t*t); }

    // -------- phase A: blocks 0..27 build M[ab] from feat, conv -> cv[ab]
    if (bid < 28) {
        int a = 0, b = 0;
        { int r = bid;
          for (int k = 0; k <= 6; k++) { if (r <= k) { a = k - r; b = r; break; } r -= k + 1; } }
        float cN = INVSQF[a] * INVSQF[b];
        for (int s = tid; s < NT; s += 256) {
            float g0 = feat[s] * 0.2f, g1 = feat[NT + s] * 0.2f;
            float eg = ex2(-0.5f * LOG2E * (g0*g0 + g1*g1));
            float pa = 1.f;
            for (int i = 0; i < a; i++) pa *= g0;
            float pb = 1.f;
            for (int i = 0; i < b; i++) pb *= g1;
            float val = eg * pa * pb * cN;
            W[(R_M + bid)*NT + s] = val;
            SP[(s >> 4)*17 + (s & 15)] = val;
        }
        __syncthreads();
        conv3d(SP, g32, W + (size_t)(R_CV + bid)*NT, tid);
    }
    bar += NB; gridbar(cnt, bar);

    // -------- init: scale1 (rank-28 contract), scale2 (closed form), q0, u
    {
        int n = bid * 256 + tid;
        if (n < NT) {
            float rs = 0.f;
#pragma unroll
            for (int ab = 0; ab < 28; ab++)
                rs = fmaf(W[(R_M+ab)*NT + n], W[(R_CV+ab)*NT + n], rs);
            float s1 = rsqrtf(rs);
            int x = n >> 8, y = (n >> 4) & 15, z = n & 15;
            float Sx = 0.f, Sy = 0.f, Sz = 0.f;
            for (int j = 0; j < 32; j++) { float d = (float)(x-j)*INVA; Sx += ex2(-0.5f*d*d); }
            for (int j = 0; j < 16; j++) { float d = (float)(y-j)*INVA; Sy += ex2(-0.5f*d*d); }
            for (int j = 0; j < 16; j++) { float d = (float)(z-j)*INVA; Sz += ex2(-0.5f*d*d); }
            float s2 = rsqrtf(Sx * Sy * Sz);
            W[R_S1*NT+n] = s1; W[R_S2*NT+n] = s2;
            float l0 = lu[n], l1 = lu[NT+n], l2 = lu[2*NT+n], l3 = lu[3*NT+n];
            float mx = fmaxf(fmaxf(l0,l1), fmaxf(l2,l3));
            float q0 = __expf(l0-mx), q1 = __expf(l1-mx), q2 = __expf(l2-mx), q3 = __expf(l3-mx);
            float inv = 1.f / (q0+q1+q2+q3);
            q0*=inv; q1*=inv; q2*=inv; q3*=inv;
            W[(R_U1+0)*NT+n]=q0*s1; W[(R_U1+1)*NT+n]=q1*s1; W[(R_U1+2)*NT+n]=q2*s1; W[(R_U1+3)*NT+n]=q3*s1;
            W[(R_U2+0)*NT+n]=q0*s2; W[(R_U2+1)*NT+n]=q1*s2; W[(R_U2+2)*NT+n]=q2*s2; W[(R_U2+3)*NT+n]=q3*s2;
        }
    }

    // -------- 5 mean-field iterations
    for (int it = 0; it < 5; it++) {
        bar += NB; gridbar(cnt, bar);      // u ready -> conv may read
        // conv phase: block bid owns one volume
        if (bid < 112) {
            const float* Mr = W + (size_t)(R_M  + (bid >> 2)) * NT;
            const float* ur = W + (size_t)(R_U1 + (bid & 3)) * NT;
            for (int s = tid; s < NT; s += 256)
                SP[(s >> 4)*17 + (s & 15)] = Mr[s] * ur[s];
        } else {
            const float* ur = W + (size_t)(R_U2 + (bid - 112)) * NT;
            for (int s = tid; s < NT; s += 256)
                SP[(s >> 4)*17 + (s & 15)] = ur[s];
        }
        __syncthreads();
        conv3d(SP, g32, W + (size_t)(R_CV + bid)*NT, tid);
        bar += NB; gridbar(cnt, bar);      // cv ready -> fuse may read

        // fuse phase: rank-28 contract + combine + compat + softmax + next u
        int n = bid * 256 + tid;
        if (n < NT) {
            float s1 = W[R_S1*NT+n], s2 = W[R_S2*NT+n];
            float y1[4] = {0.f, 0.f, 0.f, 0.f};
#pragma unroll
            for (int ab = 0; ab < 28; ab++) {
                float m = W[(R_M+ab)*NT + n];
#pragma unroll
                for (int c = 0; c < 4; c++)
                    y1[c] = fmaf(m, W[(R_CV + ab*4 + c)*NT + n], y1[c]);
            }
            float comb[4], q[4];
#pragma unroll
            for (int c = 0; c < 4; c++)
                comb[c] = s1 * y1[c] + s2 * W[(R_CV + 112 + c)*NT + n];
#pragma unroll
            for (int o = 0; o < 4; o++) {
                float upd = 0.f;
#pragma unroll
                for (int c = 0; c < 4; c++) upd = fmaf(compat[o*4+c], comb[c], upd);
                q[o] = lu[o*NT+n] - upd;
            }
            float mx = fmaxf(fmaxf(q[0],q[1]), fmaxf(q[2],q[3]));
            float sum = 0.f;
#pragma unroll
            for (int c = 0; c < 4; c++) { q[c] = __expf(q[c]-mx); sum += q[c]; }
            float inv = 1.f / sum;
#pragma unroll
            for (int c = 0; c < 4; c++) {
                q[c] *= inv;
                if (it == 4) {
                    out[c*NT+n] = q[c];
                } else {
                    W[(R_U1+c)*NT+n] = q[c]*s1;
                    W[(R_U2+c)*NT+n] = q[c]*s2;
                }
            }
        }
    }
}

// ---------------------------------------------------------------- driver
extern "C" void kernel_launch(void* const* d_in, const int* in_sizes, int n_in,
                              void* d_out, int out_size, void* d_ws, size_t ws_size,
                              hipStream_t stream) {
    const float* lu     = (const float*)d_in[0];
    const float* feat   = (const float*)d_in[1];
    const float* compat = (const float*)d_in[2];
    float* out = (float*)d_out;
    float* W   = (float*)d_ws;          // uses 155 rows * 32 KB ~= 5.1 MB

    // zero the grid-barrier counter (memset node is graph-capture safe)
    hipMemsetAsync((char*)d_ws + (size_t)R_CNT * NT * sizeof(float), 0, 64, stream);
    k_mega<<<dim3(NB), dim3(256), 0, stream>>>(lu, feat, compat, out, W);
}

// Round 5
// 346.884 us; speedup vs baseline: 1.6562x; 1.6562x over previous
//
#include <hip/hip_runtime.h>
#include <math.h>

// CRF mean-field, fully factorized (rank-28 Taylor of exp(g.g') x separable
// 3-D Gaussian convs), ONE persistent kernel with hand-rolled grid barriers.
// 116 blocks <= 256 CUs => co-resident. Barrier counter is monotonic
// (epoch-based); memset node zeroes it before each replay.
// R4 lesson: polling with an agent-scope atomic LOAD observed stale per-XCD
// L2 data (~48us/barrier, eviction-paced). Poll with atomicAdd(cnt,0) RMW
// instead — RMWs execute at the memory-side coherence point (always fresh).

constexpr int   NT    = 8192;
constexpr int   NB    = 116;                 // 112 bilateral + 4 spatial volumes
constexpr float SQL2E = 1.2011224087864498f; // sqrt(log2 e)
constexpr float LOG2E = 1.4426950408889634f;
constexpr float INVA  = 0.2f * SQL2E;        // spatial prescale

// W rows (NT floats): 0..27 M[ab] | 28 s1 | 29 s2 | 30..33 u1 | 34..37 u2
//                     38..153 cv  | 154 barrier counter
constexpr int R_M = 0, R_S1 = 28, R_S2 = 29, R_U1 = 30, R_U2 = 34, R_CV = 38;
constexpr int R_CNT = 154;

__constant__ float INVSQF[7] = {1.f, 1.f, 0.70710678f, 0.40824829f,
                                0.20412415f, 0.09128709f, 0.03726780f};

static __device__ __forceinline__ float ex2(float x) {
    return __builtin_amdgcn_exp2f(x);
}

static __device__ __forceinline__ void gridbar(unsigned* cnt, unsigned target) {
    __syncthreads();
    if (threadIdx.x == 0) {
        __threadfence();                       // release: publish block's writes
        unsigned prev = atomicAdd(cnt, 1u);
        if (prev + 1u < target) {
            do {
                __builtin_amdgcn_s_sleep(4);   // ~256 cyc backoff
            } while (atomicAdd(cnt, 0u) < target);   // RMW poll: always fresh
        }
        __threadfence();                       // acquire side
    }
    __syncthreads();
}

// Separable 3-D Gaussian conv of the volume in SP (512x17-padded), in place,
// result written to global row outp. Layout n = x*256 + y*16 + z.
static __device__ __forceinline__ void conv3d(float* SP, const float* g32,
                                              float* __restrict__ outp, int tid) {
    // z-pass: rows (x,y) at stride 17
#pragma unroll
    for (int rr = 0; rr < 2; rr++) {
        int r = tid + rr * 256;
        float v[16], acc[16];
#pragma unroll
        for (int z = 0; z < 16; z++) { v[z] = SP[r*17 + z]; acc[z] = 0.f; }
#pragma unroll
        for (int zp = 0; zp < 16; zp++)
#pragma unroll
            for (int z = 0; z < 16; z++) {
                int d = (z > zp) ? (z - zp) : (zp - z);
                acc[z] = fmaf(g32[d], v[zp], acc[z]);
            }
#pragma unroll
        for (int z = 0; z < 16; z++) SP[r*17 + z] = acc[z];
    }
    __syncthreads();
    // y-pass: rows (x,z), stride 17 between y's
#pragma unroll
    for (int rr = 0; rr < 2; rr++) {
        int r = tid + rr * 256;
        int base = (r >> 4) * 272 + (r & 15);
        float v[16], acc[16];
#pragma unroll
        for (int y = 0; y < 16; y++) { v[y] = SP[base + y*17]; acc[y] = 0.f; }
#pragma unroll
        for (int yp = 0; yp < 16; yp++)
#pragma unroll
            for (int y = 0; y < 16; y++) {
                int d = (y > yp) ? (y - yp) : (yp - y);
                acc[y] = fmaf(g32[d], v[yp], acc[y]);
            }
#pragma unroll
        for (int y = 0; y < 16; y++) SP[base + y*17] = acc[y];
    }
    __syncthreads();
    // x-pass: rows (y,z), stride 272; write to global
    {
        int base = (tid >> 4) * 17 + (tid & 15);
        float v[32], acc[32];
#pragma unroll
        for (int xp = 0; xp < 32; xp++) { v[xp] = SP[base + xp*272]; acc[xp] = 0.f; }
#pragma unroll
        for (int xp = 0; xp < 32; xp++)
#pragma unroll
            for (int x = 0; x < 32; x++) {
                int d = (x > xp) ? (x - xp) : (xp - x);
                acc[x] = fmaf(g32[d], v[xp], acc[x]);
            }
#pragma unroll
        for (int x = 0; x < 32; x++) outp[x*256 + tid] = acc[x];
    }
}

__global__ __launch_bounds__(256) void k_mega(const float* __restrict__ lu,
        const float* __restrict__ feat, const float* __restrict__ compat,
        float* __restrict__ out, float* __restrict__ W) {
    __shared__ float SP[512 * 17];
    const int bid = blockIdx.x, tid = threadIdx.x;
    unsigned* cnt = (unsigned*)(W + (size_t)R_CNT * NT);
    unsigned bar = 0;
    float g32[32];
#pragma unroll
    for (int d = 0; d < 32; d++) { float t = d * INVA; g32[d] = ex2(-0.5f*t*t); }

    // -------- phase A: blocks 0..27 build M[ab] from feat, conv -> cv[ab]
    if (bid < 28) {
        int a = 0, b = 0;
        { int r = bid;
          for (int k = 0; k <= 6; k++) { if (r <= k) { a = k - r; b = r; break; } r -= k + 1; } }
        float cN = INVSQF[a] * INVSQF[b];
        for (int s = tid; s < NT; s += 256) {
            float g0 = feat[s] * 0.2f, g1 = feat[NT + s] * 0.2f;
            float eg = ex2(-0.5f * LOG2E * (g0*g0 + g1*g1));
            float pa = 1.f;
            for (int i = 0; i < a; i++) pa *= g0;
            float pb = 1.f;
            for (int i = 0; i < b; i++) pb *= g1;
            float val = eg * pa * pb * cN;
            W[(R_M + bid)*NT + s] = val;
            SP[(s >> 4)*17 + (s & 15)] = val;
        }
        __syncthreads();
        conv3d(SP, g32, W + (size_t)(R_CV + bid)*NT, tid);
    }
    bar += NB; gridbar(cnt, bar);

    // -------- init: scale1 (rank-28 contract), scale2 (closed form), q0, u
    {
        int n = bid * 256 + tid;
        if (n < NT) {
            float rs = 0.f;
#pragma unroll
            for (int ab = 0; ab < 28; ab++)
                rs = fmaf(W[(R_M+ab)*NT + n], W[(R_CV+ab)*NT + n], rs);
            float s1 = rsqrtf(rs);
            int x = n >> 8, y = (n >> 4) & 15, z = n & 15;
            float Sx = 0.f, Sy = 0.f, Sz = 0.f;
            for (int j = 0; j < 32; j++) { float d = (float)(x-j)*INVA; Sx += ex2(-0.5f*d*d); }
            for (int j = 0; j < 16; j++) { float d = (float)(y-j)*INVA; Sy += ex2(-0.5f*d*d); }
            for (int j = 0; j < 16; j++) { float d = (float)(z-j)*INVA; Sz += ex2(-0.5f*d*d); }
            float s2 = rsqrtf(Sx * Sy * Sz);
            W[R_S1*NT+n] = s1; W[R_S2*NT+n] = s2;
            float l0 = lu[n], l1 = lu[NT+n], l2 = lu[2*NT+n], l3 = lu[3*NT+n];
            float mx = fmaxf(fmaxf(l0,l1), fmaxf(l2,l3));
            float q0 = __expf(l0-mx), q1 = __expf(l1-mx), q2 = __expf(l2-mx), q3 = __expf(l3-mx);
            float inv = 1.f / (q0+q1+q2+q3);
            q0*=inv; q1*=inv; q2*=inv; q3*=inv;
            W[(R_U1+0)*NT+n]=q0*s1; W[(R_U1+1)*NT+n]=q1*s1; W[(R_U1+2)*NT+n]=q2*s1; W[(R_U1+3)*NT+n]=q3*s1;
            W[(R_U2+0)*NT+n]=q0*s2; W[(R_U2+1)*NT+n]=q1*s2; W[(R_U2+2)*NT+n]=q2*s2; W[(R_U2+3)*NT+n]=q3*s2;
        }
    }

    // -------- 5 mean-field iterations
    for (int it = 0; it < 5; it++) {
        bar += NB; gridbar(cnt, bar);      // u ready -> conv may read
        if (bid < 112) {
            const float* Mr = W + (size_t)(R_M  + (bid >> 2)) * NT;
            const float* ur = W + (size_t)(R_U1 + (bid & 3)) * NT;
            for (int s = tid; s < NT; s += 256)
                SP[(s >> 4)*17 + (s & 15)] = Mr[s] * ur[s];
        } else {
            const float* ur = W + (size_t)(R_U2 + (bid - 112)) * NT;
            for (int s = tid; s < NT; s += 256)
                SP[(s >> 4)*17 + (s & 15)] = ur[s];
        }
        __syncthreads();
        conv3d(SP, g32, W + (size_t)(R_CV + bid)*NT, tid);
        bar += NB; gridbar(cnt, bar);      // cv ready -> fuse may read

        int n = bid * 256 + tid;
        if (n < NT) {
            float s1 = W[R_S1*NT+n], s2 = W[R_S2*NT+n];
            float y1[4] = {0.f, 0.f, 0.f, 0.f};
#pragma unroll
            for (int ab = 0; ab < 28; ab++) {
                float m = W[(R_M+ab)*NT + n];
#pragma unroll
                for (int c = 0; c < 4; c++)
                    y1[c] = fmaf(m, W[(R_CV + ab*4 + c)*NT + n], y1[c]);
            }
            float comb[4], q[4];
#pragma unroll
            for (int c = 0; c < 4; c++)
                comb[c] = s1 * y1[c] + s2 * W[(R_CV + 112 + c)*NT + n];
#pragma unroll
            for (int o = 0; o < 4; o++) {
                float upd = 0.f;
#pragma unroll
                for (int c = 0; c < 4; c++) upd = fmaf(compat[o*4+c], comb[c], upd);
                q[o] = lu[o*NT+n] - upd;
            }
            float mx = fmaxf(fmaxf(q[0],q[1]), fmaxf(q[2],q[3]));
            float sum = 0.f;
#pragma unroll
            for (int c = 0; c < 4; c++) { q[c] = __expf(q[c]-mx); sum += q[c]; }
            float inv = 1.f / sum;
#pragma unroll
            for (int c = 0; c < 4; c++) {
                q[c] *= inv;
                if (it == 4) {
                    out[c*NT+n] = q[c];
                } else {
                    W[(R_U1+c)*NT+n] = q[c]*s1;
                    W[(R_U2+c)*NT+n] = q[c]*s2;
                }
            }
        }
    }
}

// ---------------------------------------------------------------- driver
extern "C" void kernel_launch(void* const* d_in, const int* in_sizes, int n_in,
                              void* d_out, int out_size, void* d_ws, size_t ws_size,
                              hipStream_t stream) {
    const float* lu     = (const float*)d_in[0];
    const float* feat   = (const float*)d_in[1];
    const float* compat = (const float*)d_in[2];
    float* out = (float*)d_out;
    float* W   = (float*)d_ws;          // uses 155 rows * 32 KB ~= 5.1 MB

    // zero the grid-barrier counter (memset node is graph-capture safe)
    hipMemsetAsync((char*)d_ws + (size_t)R_CNT * NT * sizeof(float), 0, 64, stream);
    k_mega<<<dim3(NB), dim3(256), 0, stream>>>(lu, feat, compat, out, W);
}